// Round 1
// baseline (28.215 us; speedup 1.0000x reference)
//
#include <hip/hip_runtime.h>
#include <math.h>

#define D_MODEL 1024
#define SEQ_L   4096
#define M_ORDER 16      // ORDER/2
#define T_CHUNK 32
#define CHUNKS_PER_ROW (SEQ_L / T_CHUNK)   // 128

// out[d*SEQ_L + t]:
//   t==0   -> h_0[d]
//   t>=1   -> sum_m r^(t-1) * (Rre*cos((t-1)*theta) - Rim*sin((t-1)*theta))
// Each thread: one d, T_CHUNK consecutive t. Per m: accurate start state at
// q0 = t0-1 (double angle reduction), then 32-step complex rotation.
__global__ __launch_bounds__(256) void pcmf_kernel(
    const float* __restrict__ r_,
    const float* __restrict__ th_,
    const float* __restrict__ Rre_,
    const float* __restrict__ Rim_,
    const float* __restrict__ h0_,
    float* __restrict__ out)
{
    const int tid = blockIdx.x * blockDim.x + threadIdx.x;
    const int d   = tid / CHUNKS_PER_ROW;      // wave-uniform (128 chunks/row)
    const int c   = tid % CHUNKS_PER_ROW;
    const int t0  = c * T_CHUNK;
    const int q0  = t0 - 1;                    // power index for j=0 (garbage at t0==0, overwritten)

    float vals[T_CHUNK];
#pragma unroll
    for (int j = 0; j < T_CHUNK; ++j) vals[j] = 0.0f;

#pragma unroll 1
    for (int m = 0; m < M_ORDER; ++m) {
        const int idx   = m * D_MODEL + d;
        const float r   = r_[idx];
        const float th  = th_[idx];
        const float Rre = Rre_[idx];
        const float nRim = -Rim_[idx];

        // per-step rotation factors
        float sn, cs;
        sincosf(th, &sn, &cs);
        const float cr = r * cs;
        const float sr = r * sn;

        // start state at q0: r^q0 * (cos(q0*th), sin(q0*th))
        const double a0  = (double)q0 * (double)th;
        const double n   = floor(a0 * 0.15915494309189535);  // a0 / (2*pi)
        const float  ang = (float)(a0 - n * 6.283185307179586);
        float s0, c0;
        sincosf(ang, &s0, &c0);
        const float dec = exp2f((float)q0 * log2f(r));       // underflows to 0 like ref
        float x = dec * c0;
        float y = dec * s0;

#pragma unroll
        for (int j = 0; j < T_CHUNK; ++j) {
            vals[j] = fmaf(Rre,  x, vals[j]);
            vals[j] = fmaf(nRim, y, vals[j]);
            const float ys = y * sr;
            const float yc = y * cr;
            const float xn = fmaf(x, cr, -ys);
            y = fmaf(x, sr, yc);
            x = xn;
        }
    }

    if (t0 == 0) vals[0] = h0_[d];

    float4* outv = (float4*)(out + (size_t)d * SEQ_L + t0);
#pragma unroll
    for (int j4 = 0; j4 < T_CHUNK / 4; ++j4) {
        outv[j4] = make_float4(vals[4*j4], vals[4*j4+1], vals[4*j4+2], vals[4*j4+3]);
    }
}

extern "C" void kernel_launch(void* const* d_in, const int* in_sizes, int n_in,
                              void* d_out, int out_size, void* d_ws, size_t ws_size,
                              hipStream_t stream) {
    // inputs: [0]=L (scalar), [1]=r, [2]=theta, [3]=R_re, [4]=R_im, [5]=h_0
    const float* r_   = (const float*)d_in[1];
    const float* th_  = (const float*)d_in[2];
    const float* Rre_ = (const float*)d_in[3];
    const float* Rim_ = (const float*)d_in[4];
    const float* h0_  = (const float*)d_in[5];
    float* out = (float*)d_out;

    const int total_threads = D_MODEL * CHUNKS_PER_ROW;   // 131072
    const int block = 256;
    const int grid = total_threads / block;               // 512
    pcmf_kernel<<<grid, block, 0, stream>>>(r_, th_, Rre_, Rim_, h0_, out);
}